// Round 8
// baseline (2382.169 us; speedup 1.0000x reference)
//
#include <hip/hip_runtime.h>
#include <math.h>

typedef _Float16 h2_t  __attribute__((ext_vector_type(2)));
typedef _Float16 h4_t  __attribute__((ext_vector_type(4)));
typedef _Float16 h8_t  __attribute__((ext_vector_type(8)));
typedef float    f4_t  __attribute__((ext_vector_type(4)));
typedef unsigned int u4_t __attribute__((ext_vector_type(4)));

#define T_ 512
#define B_ 64
#define E_ 256
#define H_ 256
#define G_ 1024   // 4*H
#define K_ 16
#define NEG_ (-10000.0f)
#define START_ 14
#define STOP_ 15

static __device__ __forceinline__ float fsig(float x) {
    return __builtin_amdgcn_rcpf(1.f + __builtin_amdgcn_exp2f(-1.4426950408889634f * x));
}
static __device__ __forceinline__ float ftanh(float x) {
    return 1.f - 2.f * __builtin_amdgcn_rcpf(1.f + __builtin_amdgcn_exp2f(2.8853900817779268f * x));
}

// ---------------------------------------------------------------------------
// Prep: pack weights (unchanged — correctness-verified).
//  wregB: h8 idx = ((dir*64 + mt)*8 + kt)*64 + lane, mt = 0..63
//         gate-interleaved rows: u = mt*4 + ((lane&15)>>2), γ = (lane&15)&3,
//         global w_hh row = γ*256 + u; k = kt*32 + (lane>>4)*8 + e.   -> 1 MB
//  wih16: [dir][row 0..1023][k 0..255] fp16 copy of w_ih              -> 1 MB
// ---------------------------------------------------------------------------
__global__ __launch_bounds__(256)
void prep_weights(const float* __restrict__ w_hh_f,
                  const float* __restrict__ w_hh_b,
                  const float* __restrict__ w_ih_f,
                  const float* __restrict__ w_ih_b,
                  _Float16* __restrict__ wregB,
                  _Float16* __restrict__ wih16)
{
    const int blk = blockIdx.x, tid = threadIdx.x;
    if (blk < 256) {                      // wregB: 65536 h8 entries
        int e    = blk * 256 + tid;
        int lane = e & 63;
        int kt   = (e >> 6) & 7;
        int mt   = (e >> 9) & 63;
        int dir  = (e >> 15) & 1;
        int l15  = lane & 15;
        int row  = (l15 & 3) * 256 + mt * 4 + (l15 >> 2);
        int k    = kt * 32 + (lane >> 4) * 8;
        const float* src = (dir ? w_hh_b : w_hh_f) + (size_t)row * 256 + k;
        h8_t o;
        #pragma unroll
        for (int i = 0; i < 8; ++i) o[i] = (_Float16)src[i];
        ((h8_t*)wregB)[e] = o;
    } else {                              // wih16: 65536 x h8
        int idx = (blk - 256) * 256 + tid;
        int dir = idx / 32768, rem = idx % 32768;
        const float* src = (dir ? w_ih_b : w_ih_f) + (size_t)rem * 8;
        _Float16* dst = wih16 + (size_t)idx * 8;
        #pragma unroll
        for (int i = 0; i < 8; ++i) dst[i] = (_Float16)src[i];
    }
}

// ---------------------------------------------------------------------------
// Kernel A: input-gate GEMM via f16 MFMA 16x16x32, bias pre-added (proven).
// Output layout: gin2[dir][t][gcol 0..1023][b 0..63], h4-contiguous in b.
// ---------------------------------------------------------------------------
__global__ __launch_bounds__(256)
void gates_mfma(const int* __restrict__ sentence,
                const float* __restrict__ emb,
                const _Float16* __restrict__ wih16,
                const float* __restrict__ b_f,
                const float* __restrict__ b_b,
                _Float16* __restrict__ gin_f,
                _Float16* __restrict__ gin_b)
{
    __shared__ _Float16 As[64 * 264];
    __shared__ _Float16 Bs[256 * 40];
    __shared__ int sidx[64];

    const int bm  = blockIdx.x;           // t
    const int dir = blockIdx.y;
    const int tid = threadIdx.x;

    const _Float16* __restrict__ wih = wih16 + (size_t)dir * 262144;
    const float*    __restrict__ bsd = dir ? b_b : b_f;
    _Float16* __restrict__ gout      = dir ? gin_b : gin_f;

    if (tid < 64) sidx[tid] = sentence[tid * T_ + bm];
    __syncthreads();

    {   // stage A (emb gather, fp32 -> fp16)
        const int r = tid & 63, kq = tid >> 6;
        const float4* src = (const float4*)(emb + (size_t)sidx[r] * 256 + kq * 64);
        _Float16* dst = As + r * 264 + kq * 64;
        #pragma unroll
        for (int c = 0; c < 8; ++c) {
            float4 v0 = src[2 * c], v1 = src[2 * c + 1];
            h8_t o;
            o[0] = (_Float16)v0.x; o[1] = (_Float16)v0.y;
            o[2] = (_Float16)v0.z; o[3] = (_Float16)v0.w;
            o[4] = (_Float16)v1.x; o[5] = (_Float16)v1.y;
            o[6] = (_Float16)v1.z; o[7] = (_Float16)v1.w;
            *(h8_t*)(dst + c * 8) = o;
        }
    }

    const int wave = tid >> 6, lane = tid & 63;
    const int l15 = lane & 15, quad = lane >> 4;

    for (int pass = 0; pass < 4; ++pass) {
        const int n0 = pass * 256;
        f4_t acc[16];
        #pragma unroll
        for (int nt = 0; nt < 16; ++nt) acc[nt] = (f4_t){0.f, 0.f, 0.f, 0.f};

        for (int kc = 0; kc < 8; ++kc) {
            __syncthreads();
            {
                const h8_t* bsrc = (const h8_t*)(wih + (size_t)(n0 + tid) * 256 + kc * 32);
                #pragma unroll
                for (int c = 0; c < 4; ++c)
                    *(h8_t*)(Bs + tid * 40 + c * 8) = bsrc[c];
            }
            __syncthreads();
            h8_t a = *(const h8_t*)(As + (wave * 16 + l15) * 264 + kc * 32 + quad * 8);
            #pragma unroll
            for (int nt = 0; nt < 16; ++nt) {
                h8_t b = *(const h8_t*)(Bs + (nt * 16 + l15) * 40 + quad * 8);
                acc[nt] = __builtin_amdgcn_mfma_f32_16x16x32_f16(a, b, acc[nt], 0, 0, 0);
            }
        }

        const size_t tbase = (size_t)bm * 65536;
        const int brow = wave * 16 + quad * 4;         // batch base (4 consec)
        #pragma unroll
        for (int nt = 0; nt < 16; ++nt) {
            const int col = n0 + nt * 16 + l15;        // gate col 0..1023
            const float bias = bsd[col];
            h4_t o4;
            #pragma unroll
            for (int r = 0; r < 4; ++r) o4[r] = (_Float16)(acc[nt][r] + bias);
            *(h4_t*)(gout + tbase + (size_t)col * 64 + brow) = o4;
        }
    }
}

// ---------------------------------------------------------------------------
// Kernel A2: IN-PLACE repack gin2 [t][gcol][b] -> ginL (unchanged, verified).
//   half idx = ((bq*512 + thr)*4 + γ)*8 + j,
//   value    = gin2[t][γ*256 + (32*(thr>>6) + 4*j + ((thr>>4)&3))][bq*16 + (thr&15)]
// ---------------------------------------------------------------------------
__global__ __launch_bounds__(256)
void repack_gin(_Float16* __restrict__ gin_f, _Float16* __restrict__ gin_b)
{
    __shared__ _Float16 S[65536];         // 128 KB
    const int t = blockIdx.x, dir = blockIdx.y, tid = threadIdx.x;
    _Float16* base = (dir ? gin_b : gin_f) + (size_t)t * 65536;

    #pragma unroll
    for (int i = 0; i < 32; ++i)
        *(h8_t*)(S + (size_t)(i * 256 + tid) * 8) =
            *(const h8_t*)(base + (size_t)(i * 256 + tid) * 8);
    __syncthreads();

    #pragma unroll
    for (int i = 0; i < 32; ++i) {
        int o   = i * 256 + tid;
        int g   = o & 3;
        int thr = (o >> 2) & 511;
        int bq  = o >> 11;
        int w   = thr >> 6, qq = (thr >> 4) & 3, n = thr & 15;
        int b   = bq * 16 + n;
        h8_t v;
        #pragma unroll
        for (int j = 0; j < 8; ++j)
            v[j] = S[(g * 256 + 32 * w + 4 * j + qq) * 64 + b];
        *(h8_t*)(base + (size_t)o * 8) = v;
    }
}

// ---------------------------------------------------------------------------
// Kernel B: zero-communication single-CU LSTM, v3: AGPR-DIRECT MFMA.
// Identical structure to rounds 6-7 (correctness-verified). The one change:
// the 48 A-fragments are loaded with "=a"-constrained volatile asm
// (global_load direct to AGPR) and consumed by the MFMA asm via the "a"
// constraint — v_mfma reads its A operand from the AGPR file NATIVELY on
// gfx950 (cdna4_isa §10), so the ~192 v_accvgpr_read copies per thread per
// step that R7's "v" constraints forced (VGPR_Count=128 cap + 22ms
// first-dispatch scratch-alloc anomaly) are eliminated. Budget: 192 AGPR
// (A) + ~60 arch VGPR (working) = 252 <= 256/wave at 2 waves/SIMD.
// Hazard handling unchanged (proven): s_nop 1 before first MFMA after
// VALU-zeroed C; s_nop 7 x2 fence before the VALU epilogue reads acc.
// ---------------------------------------------------------------------------
#define MFMA1(ACC, A, BF) \
    asm("s_nop 1\n\tv_mfma_f32_16x16x32_f16 %0, %1, %2, %0" \
        : "+v"(ACC) : "a"(A), "v"(BF))
#define MFMA(ACC, A, BF) \
    asm("v_mfma_f32_16x16x32_f16 %0, %1, %2, %0" \
        : "+v"(ACC) : "a"(A), "v"(BF))
#define MFMA1V(ACC, A, BF) \
    asm("s_nop 1\n\tv_mfma_f32_16x16x32_f16 %0, %1, %2, %0" \
        : "+v"(ACC) : "v"(A), "v"(BF))
#define MFMAV(ACC, A, BF) \
    asm("v_mfma_f32_16x16x32_f16 %0, %1, %2, %0" \
        : "+v"(ACC) : "v"(A), "v"(BF))
#define MFENCE4(A0, A1, A2, A3) \
    asm("s_nop 7\n\ts_nop 7" : "+v"(A0), "+v"(A1), "+v"(A2), "+v"(A3))

#define EPI(JG, AJ, V0, V1, V2, V3, JL) do {                                  \
    float gi = AJ[0] + (float)(V0)[JL];                                       \
    float gf = AJ[1] + (float)(V1)[JL];                                       \
    float gg = AJ[2] + (float)(V2)[JL];                                       \
    float go = AJ[3] + (float)(V3)[JL];                                       \
    float si = fsig(gi), sf = fsig(gf), so = fsig(go);                        \
    cst[JG] = sf * cst[JG] + si * ftanh(gg);                                  \
    float hv = so * ftanh(cst[JG]);                                           \
    hp[(JG) * 4] = hv;                                                        \
    float hn = __shfl_down(hv, 16, 64);                                       \
    if ((q & 1) == 0) {                                                       \
        int uu = 32 * w + 4 * (JG) + q;                                       \
        int pu = ((uu >> 5) << 8) | (((uu >> 3) & 3) << 6) |                  \
                 (n << 2) | ((uu >> 1) & 3);                                  \
        h2_t pk; pk[0] = (_Float16)hv; pk[1] = (_Float16)hn;                  \
        BsU[bnext + pu] = __builtin_bit_cast(unsigned int, pk);               \
    }                                                                         \
} while (0)

__global__ __attribute__((amdgpu_flat_work_group_size(512, 512),
                          amdgpu_waves_per_eu(2, 2)))
void lstm_full(const _Float16* __restrict__ ginL_f,
               const _Float16* __restrict__ ginL_b,
               const _Float16* __restrict__ wregB,
               float* __restrict__ hf, float* __restrict__ hb)
{
    __shared__ _Float16 ALds[65536];      // 128 KB: A-frags j=6,7 per wave
    __shared__ unsigned int BsU[4096];    // 16 KB: 2 x 2048-uint B images

    const int id  = blockIdx.x;           // dir*4 + bq
    const int dir = id >> 2;
    const int bq  = id & 3;
    const int t   = threadIdx.x;          // 0..511
    const int w   = t >> 6, lane = t & 63;
    const int n   = lane & 15, q = lane >> 4;

    const _Float16* __restrict__ gin  = dir ? ginL_b : ginL_f;
    float*          __restrict__ hout = dir ? hb : hf;

    // ---- stage LDS A-fragments (m-tiles 8w+6, 8w+7) ----
    {
        const h8_t* src = (const h8_t*)wregB +
                          ((size_t)(dir * 64 + 8 * w + 6) * 8) * 64 + lane;
        #pragma unroll
        for (int jj = 0; jj < 2; ++jj)
            #pragma unroll
            for (int kt = 0; kt < 8; ++kt)
                *(h8_t*)(ALds + (size_t)((((w * 2 + jj) * 8) + kt) * 64 + lane) * 8) =
                    src[(jj * 8 + kt) * 64];
    }

    // ---- 48 A-fragments (m-tiles 8w..8w+5): loaded DIRECT TO AGPR ----
    const h8_t* wp = (const h8_t*)wregB +
                     ((size_t)(dir * 64 + 8 * w) * 8) * 64 + lane;
    u4_t Au[48];
    #pragma unroll
    for (int jk = 0; jk < 48; ++jk) {
        const void* p0 = (const void*)(wp + jk * 64);
        asm volatile("global_load_dwordx4 %0, %1, off\n\ts_waitcnt vmcnt(0)"
                     : "=a"(Au[jk]) : "v"(p0));
    }

    const int b  = bq * 16 + n;
    const int s0 = dir ? (T_ - 1) : 0;
    const long gstep = (dir ? -1L : 1L) * 65536;
    const _Float16* gp = gin + (size_t)s0 * 65536 + (size_t)(bq * 512 + t) * 32;
    float* hp = hout + ((size_t)s0 * 64 + b) * 256 + 32 * w + q;
    const long hstep = (dir ? -1L : 1L) * (64 * 256);

    const int al0 = (((w * 2 + 0) * 8) * 64 + lane) * 8;   // half-index bases
    const int al1 = (((w * 2 + 1) * 8) * 64 + lane) * 8;

    BsU[t] = 0u; BsU[t + 512] = 0u; BsU[t + 1024] = 0u; BsU[t + 1536] = 0u;
    float cst[8];
    #pragma unroll
    for (int j = 0; j < 8; ++j) cst[j] = 0.f;
    int p = 0;
    __syncthreads();

    for (int s = 0; s < T_; ++s) {
        // gin low halves (j=0..3 of each gate γ) — issued early
        uint2 gl0 = *(const uint2*)(gp + 0);
        uint2 gl1 = *(const uint2*)(gp + 8);
        uint2 gl2 = *(const uint2*)(gp + 16);
        uint2 gl3 = *(const uint2*)(gp + 24);

        const _Float16* Bb = (const _Float16*)BsU + (size_t)p * 4096;
        const int bnext = (p ^ 1) * 2048;

        f4_t a0 = (f4_t){0.f, 0.f, 0.f, 0.f};
        f4_t a1 = a0, a2 = a0, a3 = a0;

        // ================= group 0: j = 0..3 (AGPR A) =================
        {
            h8_t bf = *(const h8_t*)(Bb + lane * 8);
            MFMA1(a0, Au[0],  bf); MFMA1(a1, Au[8],  bf);
            MFMA1(a2, Au[16], bf); MFMA1(a3, Au[24], bf);
        }
        #pragma unroll
        for (int kt = 1; kt < 8; ++kt) {
            h8_t bf = *(const h8_t*)(Bb + kt * 512 + lane * 8);
            MFMA(a0, Au[kt],      bf); MFMA(a1, Au[8 + kt],  bf);
            MFMA(a2, Au[16 + kt], bf); MFMA(a3, Au[24 + kt], bf);
        }
        MFENCE4(a0, a1, a2, a3);

        // gin high halves issued now (hide under epilogue + group-1 chain)
        uint2 gh0 = *(const uint2*)(gp + 4);
        uint2 gh1 = *(const uint2*)(gp + 12);
        uint2 gh2 = *(const uint2*)(gp + 20);
        uint2 gh3 = *(const uint2*)(gp + 28);

        {
            h4_t L0 = __builtin_bit_cast(h4_t, gl0);
            h4_t L1 = __builtin_bit_cast(h4_t, gl1);
            h4_t L2 = __builtin_bit_cast(h4_t, gl2);
            h4_t L3 = __builtin_bit_cast(h4_t, gl3);
            EPI(0, a0, L0, L1, L2, L3, 0);
            EPI(1, a1, L0, L1, L2, L3, 1);
            EPI(2, a2, L0, L1, L2, L3, 2);
            EPI(3, a3, L0, L1, L2, L3, 3);
        }

        // ========== group 1: j = 4..7 (j=4,5 AGPR; j=6,7 LDS->VGPR) ==========
        a0 = (f4_t){0.f, 0.f, 0.f, 0.f};
        a1 = a0; a2 = a0; a3 = a0;
        {
            h8_t bf = *(const h8_t*)(Bb + lane * 8);
            h8_t x6 = *(const h8_t*)(ALds + al0);
            h8_t x7 = *(const h8_t*)(ALds + al1);
            MFMA1(a0, Au[32], bf); MFMA1(a1, Au[40], bf);
            MFMA1V(a2, x6, bf);    MFMA1V(a3, x7, bf);
        }
        #pragma unroll
        for (int kt = 1; kt < 8; ++kt) {
            h8_t bf = *(const h8_t*)(Bb + kt * 512 + lane * 8);
            h8_t x6 = *(const h8_t*)(ALds + al0 + kt * 512);
            h8_t x7 = *(const h8_t*)(ALds + al1 + kt * 512);
            MFMA(a0, Au[32 + kt], bf); MFMA(a1, Au[40 + kt], bf);
            MFMAV(a2, x6, bf);         MFMAV(a3, x7, bf);
        }
        MFENCE4(a0, a1, a2, a3);

        {
            h4_t H0 = __builtin_bit_cast(h4_t, gh0);
            h4_t H1 = __builtin_bit_cast(h4_t, gh1);
            h4_t H2 = __builtin_bit_cast(h4_t, gh2);
            h4_t H3 = __builtin_bit_cast(h4_t, gh3);
            EPI(4, a0, H0, H1, H2, H3, 0);
            EPI(5, a1, H0, H1, H2, H3, 1);
            EPI(6, a2, H0, H1, H2, H3, 2);
            EPI(7, a3, H0, H1, H2, H3, 3);
        }

        gp += gstep;
        hp += hstep;
        __syncthreads();                   // next-step B image complete
        p ^= 1;
    }
}

// ---------------------------------------------------------------------------
// Kernel C: feats[m, o] = concat(hf[m], hb[m]) . w_out[o, :] + b_out[o]
// ---------------------------------------------------------------------------
__global__ __launch_bounds__(256)
void feats_proj(const float* __restrict__ hf, const float* __restrict__ hb,
                const float* __restrict__ w_out, const float* __restrict__ b_out,
                float* __restrict__ feats)
{
    const int lane = threadIdx.x & 63;
    const int wv   = threadIdx.x >> 6;
    const int m    = blockIdx.x * 4 + wv;
    const int o    = lane & 15;
    const int qq   = lane >> 4;

    const float* hsrc = (qq < 2) ? (hf + (size_t)m * 256 + qq * 128)
                                 : (hb + (size_t)m * 256 + (qq - 2) * 128);
    const float4* h4 = (const float4*)hsrc;
    const float4* w4 = (const float4*)(w_out + o * 512 + qq * 128);

    float acc = 0.f;
    #pragma unroll
    for (int i = 0; i < 32; ++i) {
        float4 hv = h4[i], wvv = w4[i];
        acc = fmaf(hv.x, wvv.x, acc);
        acc = fmaf(hv.y, wvv.y, acc);
        acc = fmaf(hv.z, wvv.z, acc);
        acc = fmaf(hv.w, wvv.w, acc);
    }
    acc += __shfl_xor(acc, 16, 64);
    acc += __shfl_xor(acc, 32, 64);
    if (lane < 16) feats[(size_t)m * 16 + o] = acc + b_out[o];
}

// ---------------------------------------------------------------------------
// Kernel D: Viterbi + backtrace.
// ---------------------------------------------------------------------------
__global__ __launch_bounds__(64)
void viterbi(const float* __restrict__ feats, const float* __restrict__ trans,
             float* __restrict__ out)
{
    __shared__ unsigned char bp[T_][16];
    const int b    = blockIdx.x;
    const int lane = threadIdx.x;
    const int l15  = lane & 15;

    float tr[16];
    #pragma unroll
    for (int p = 0; p < 16; ++p)
        tr[p] = (lane < 16) ? trans[lane * 16 + p] : 0.f;

    float fv = (lane == START_) ? 0.f : NEG_;

    for (int t4 = 0; t4 < T_; t4 += 4) {
        float fblk = feats[((size_t)(t4 + (lane >> 4)) * 64 + b) * 16 + l15];
        #pragma unroll
        for (int tt = 0; tt < 4; ++tt) {
            const int t = t4 + tt;
            float best = -3.4e38f; int arg = 0;
            #pragma unroll
            for (int p = 0; p < 16; ++p) {
                float s = __shfl(fv, p, 64) + tr[p];
                if (s > best) { best = s; arg = p; }
            }
            float ft = __shfl(fblk, tt * 16 + l15, 64);
            if (lane < 16) {
                fv = best + ft;
                bp[t][lane] = (unsigned char)arg;
            }
        }
    }

    float term = fv + ((lane < 16) ? trans[STOP_ * 16 + lane] : 0.f);
    float v  = (lane < 16) ? term : -3.4e38f;
    int  idx = (lane < 16) ? lane : (1 << 20);
    #pragma unroll
    for (int off = 1; off < 64; off <<= 1) {
        float v2 = __shfl_xor(v, off, 64);
        int   i2 = __shfl_xor(idx, off, 64);
        if (v2 > v || (v2 == v && i2 < idx)) { v = v2; idx = i2; }
    }
    __syncthreads();
    if (lane == 0) {
        out[b] = v;
        int tag = idx;
        for (int t = T_ - 1; t >= 0; --t) {
            out[64 + (size_t)t * 64 + b] = (float)tag;
            tag = bp[t][tag];
        }
    }
}

// ---------------------------------------------------------------------------
extern "C" void kernel_launch(void* const* d_in, const int* in_sizes, int n_in,
                              void* d_out, int out_size, void* d_ws, size_t ws_size,
                              hipStream_t stream) {
    const int*   sentence = (const int*)d_in[0];
    const float* emb      = (const float*)d_in[1];
    const float* w_ih_f   = (const float*)d_in[2];
    const float* w_hh_f   = (const float*)d_in[3];
    const float* b_f      = (const float*)d_in[4];
    const float* w_ih_b   = (const float*)d_in[5];
    const float* w_hh_b   = (const float*)d_in[6];
    const float* b_b      = (const float*)d_in[7];
    const float* w_out    = (const float*)d_in[8];
    const float* b_out    = (const float*)d_in[9];
    const float* trans    = (const float*)d_in[10];
    float* out = (float*)d_out;

    // workspace: gin_f|gin_b (fp16 64MB ea, repacked in place) |
    //            hf|hb (fp32 32MB ea) | feats (2MB) | wih16 (1MB) | wregB (1MB)
    _Float16* gin_f = (_Float16*)d_ws;
    _Float16* gin_b = gin_f + (size_t)T_ * B_ * G_;
    float* hf    = (float*)(gin_b + (size_t)T_ * B_ * G_);
    float* hb    = hf + (size_t)T_ * B_ * H_;
    float* feats = hb + (size_t)T_ * B_ * H_;
    _Float16* wih16 = (_Float16*)(feats + (size_t)T_ * B_ * K_);
    _Float16* wregB = wih16 + 524288;

    prep_weights<<<512, 256, 0, stream>>>(w_hh_f, w_hh_b, w_ih_f, w_ih_b,
                                          wregB, wih16);
    gates_mfma<<<dim3(512, 2), 256, 0, stream>>>(sentence, emb, wih16,
                                                 b_f, b_b, gin_f, gin_b);
    repack_gin<<<dim3(512, 2), 256, 0, stream>>>(gin_f, gin_b);
    lstm_full<<<8, 512, 0, stream>>>(gin_f, gin_b, wregB, hf, hb);
    feats_proj<<<8192, 256, 0, stream>>>(hf, hb, w_out, b_out, feats);
    viterbi<<<64, 64, 0, stream>>>(feats, trans, out);
}

// Round 9
// 1356.859 us; speedup vs baseline: 1.7556x; 1.7556x over previous
//
#include <hip/hip_runtime.h>
#include <math.h>

typedef _Float16 h2_t  __attribute__((ext_vector_type(2)));
typedef _Float16 h8_t  __attribute__((ext_vector_type(8)));
typedef float    f4_t  __attribute__((ext_vector_type(4)));

#define T_ 512
#define B_ 64
#define E_ 256
#define H_ 256
#define G_ 1024   // 4*H
#define K_ 16
#define NEG_ (-10000.0f)
#define START_ 14
#define STOP_ 15

#if defined(__has_builtin)
#if __has_builtin(__builtin_amdgcn_fdot2)
#define HAVE_FDOT2 1
#endif
#endif

static __device__ __forceinline__ float dot2(h2_t a, h2_t b, float c) {
#ifdef HAVE_FDOT2
    return __builtin_amdgcn_fdot2(a, b, c, false);
#else
    return fmaf((float)a[0], (float)b[0], fmaf((float)a[1], (float)b[1], c));
#endif
}

// extract h2 pair P from a wider fp16 vector — template param keeps the
// shufflevector indices integer-constant (SSA, no alloca ever).
template <int P, typename V>
static __device__ __forceinline__ h2_t get2(V v) {
    return __builtin_shufflevector(v, v, 2 * P, 2 * P + 1);
}

// ---------------------------------------------------------------------------
// Prep: pack all weights to fp16 in the layouts the hot kernels want.
//  wreg2: [d2 = dir*2+half][v=0..7][q=0..511] x 32 halves
//         (row = (q>>7)*256 + half*128 + (q&127), k = v*32)     -> 1 MB
//  wih16: [dir][row 0..1023][k 0..255] fp16 copy of w_ih        -> 1 MB
// (byte-identical to the round-1 verified version)
// ---------------------------------------------------------------------------
__global__ __launch_bounds__(256)
void prep_weights(const float* __restrict__ w_hh_f,
                  const float* __restrict__ w_hh_b,
                  const float* __restrict__ w_ih_f,
                  const float* __restrict__ w_ih_b,
                  _Float16* __restrict__ wreg2,
                  _Float16* __restrict__ wih16)
{
    const int blk = blockIdx.x, tid = threadIdx.x;
    if (blk < 64) {                       // wreg2: 16384 x h32
        int e = blk * 256 + tid;
        int q = e & 511;
        int g = e >> 9;
        int d2 = g >> 3, v = g & 7;
        int dir = d2 >> 1, half = d2 & 1;
        int row = (q >> 7) * 256 + half * 128 + (q & 127);
        const float* src = (dir ? w_hh_b : w_hh_f) + (size_t)row * 256 + v * 32;
        _Float16* dst = wreg2 + (size_t)e * 32;
        #pragma unroll
        for (int i = 0; i < 32; ++i) dst[i] = (_Float16)src[i];
    } else {                              // wih16: 65536 x h8
        int idx = (blk - 64) * 256 + tid;
        int dir = idx / 32768, rem = idx % 32768;
        const float* src = (dir ? w_ih_b : w_ih_f) + (size_t)rem * 8;
        _Float16* dst = wih16 + (size_t)idx * 8;
        #pragma unroll
        for (int i = 0; i < 8; ++i) dst[i] = (_Float16)src[i];
    }
}

// ---------------------------------------------------------------------------
// Kernel A: input-gate GEMM via f16 MFMA 16x16x32 (round-1 verified version).
// ---------------------------------------------------------------------------
__global__ __launch_bounds__(256)
void gates_mfma(const int* __restrict__ sentence,
                const float* __restrict__ emb,
                const _Float16* __restrict__ wih16,
                _Float16* __restrict__ gin_f,
                _Float16* __restrict__ gin_b)
{
    __shared__ _Float16 As[64 * 264];
    __shared__ _Float16 Bs[256 * 40];
    __shared__ int sidx[64];

    const int bm  = blockIdx.x;           // t
    const int dir = blockIdx.y;
    const int tid = threadIdx.x;

    const _Float16* __restrict__ wih = wih16 + (size_t)dir * 262144;
    _Float16* __restrict__ gout      = dir ? gin_b : gin_f;

    if (tid < 64) sidx[tid] = sentence[tid * T_ + bm];
    __syncthreads();

    {   // stage A (emb gather, fp32 -> fp16)
        const int r = tid & 63, kq = tid >> 6;
        const float4* src = (const float4*)(emb + (size_t)sidx[r] * 256 + kq * 64);
        _Float16* dst = As + r * 264 + kq * 64;
        #pragma unroll
        for (int c = 0; c < 8; ++c) {
            float4 v0 = src[2 * c], v1 = src[2 * c + 1];
            h8_t o;
            o[0] = (_Float16)v0.x; o[1] = (_Float16)v0.y;
            o[2] = (_Float16)v0.z; o[3] = (_Float16)v0.w;
            o[4] = (_Float16)v1.x; o[5] = (_Float16)v1.y;
            o[6] = (_Float16)v1.z; o[7] = (_Float16)v1.w;
            *(h8_t*)(dst + c * 8) = o;
        }
    }

    const int wave = tid >> 6, lane = tid & 63;
    const int l15 = lane & 15, quad = lane >> 4;

    for (int pass = 0; pass < 4; ++pass) {
        const int n0 = pass * 256;
        f4_t acc[16];
        #pragma unroll
        for (int nt = 0; nt < 16; ++nt) acc[nt] = (f4_t){0.f, 0.f, 0.f, 0.f};

        for (int kc = 0; kc < 8; ++kc) {
            __syncthreads();
            {
                const h8_t* bsrc = (const h8_t*)(wih + (size_t)(n0 + tid) * 256 + kc * 32);
                #pragma unroll
                for (int c = 0; c < 4; ++c)
                    *(h8_t*)(Bs + tid * 40 + c * 8) = bsrc[c];
            }
            __syncthreads();
            h8_t a = *(const h8_t*)(As + (wave * 16 + l15) * 264 + kc * 32 + quad * 8);
            #pragma unroll
            for (int nt = 0; nt < 16; ++nt) {
                h8_t b = *(const h8_t*)(Bs + (nt * 16 + l15) * 40 + quad * 8);
                acc[nt] = __builtin_amdgcn_mfma_f32_16x16x32_f16(a, b, acc[nt], 0, 0, 0);
            }
        }

        const size_t mbase = (size_t)bm * 64 + wave * 16 + quad * 4;
        #pragma unroll
        for (int nt = 0; nt < 16; ++nt) {
            const int col = n0 + nt * 16 + l15;
            #pragma unroll
            for (int r = 0; r < 4; ++r)
                gout[(mbase + r) * 1024 + col] = (_Float16)acc[nt][r];
        }
    }
}

// ---------------------------------------------------------------------------
// Kernel B: pairwise persistent LSTM — round-1 structure (best measured:
// 893 us) with ONE change: the per-thread weight row is held as 32 x h8
// (4-register tuples) instead of 8 x h32 (16-register tuples). Evidence
// from rounds 4-8: the allocator reliably keeps 4-reg tuples resident but
// rematerializes/reloads 16-reg tuples (R1: VGPR=88 with 128 demanded ->
// ~2.5x VALU issue inflation). Same memory layout, same math, same
// mailbox; single-variable experiment against the R1 champion.
// Mailbox: data-is-the-flag, sentinel 0xFFFFFFFF (fp16 NaN pair, |h|<1 so
// unreachable), relaxed agent-scope atomics (per-XCD L2 not coherent).
// All 256 blocks co-resident (1 block/CU) -> spin cannot deadlock.
// ---------------------------------------------------------------------------
#define DOT8H(WC, HV, ACC) do {                                     \
    ACC = dot2(get2<0>(WC), get2<0>(HV), ACC);                      \
    ACC = dot2(get2<1>(WC), get2<1>(HV), ACC);                      \
    ACC = dot2(get2<2>(WC), get2<2>(HV), ACC);                      \
    ACC = dot2(get2<3>(WC), get2<3>(HV), ACC);                      \
} while (0)

#define VBLK(V, VI) do {                                            \
    h8_t hv0 = HB[(VI)*4+0], hv1 = HB[(VI)*4+1];                    \
    h8_t hv2 = HB[(VI)*4+2], hv3 = HB[(VI)*4+3];                    \
    DOT8H(W##V##_0, hv0, a0); DOT8H(W##V##_1, hv1, a1);             \
    DOT8H(W##V##_2, hv2, a2); DOT8H(W##V##_3, hv3, a3);             \
} while (0)

#define LDW(V)                                                      \
    h8_t W##V##_0 = b8[((V) * 512 + q) * 4 + 0],                    \
         W##V##_1 = b8[((V) * 512 + q) * 4 + 1],                    \
         W##V##_2 = b8[((V) * 512 + q) * 4 + 2],                    \
         W##V##_3 = b8[((V) * 512 + q) * 4 + 3]

__global__ __attribute__((amdgpu_flat_work_group_size(512, 512),
                          amdgpu_waves_per_eu(2, 2)))
void lstm_pair(const _Float16* __restrict__ gin_f,
               const _Float16* __restrict__ gin_b,
               const _Float16* __restrict__ wreg2,
               const float* __restrict__ b_f,
               const float* __restrict__ b_b,
               float* __restrict__ hf, float* __restrict__ hb,
               unsigned int* __restrict__ hex)
{
    __shared__ h8_t  hbuf8[32];       // h(t) as 256 fp16
    __shared__ float gbuf[512];

    const int bid  = blockIdx.x;
    const int c16  = bid >> 4;
    const int w16  = bid & 15;
    const int half = w16 >> 3;                 // partner = bid ^ 8
    const int pair = c16 * 8 + (w16 & 7);      // 0..127
    const int dir  = pair >> 6;
    const int b    = pair & 63;
    const int q    = threadIdx.x;

    const int gcl = q >> 7, off = q & 127;
    const int row = gcl * 256 + half * 128 + off;

    const _Float16* __restrict__ gin  = dir ? gin_b : gin_f;
    const float*    __restrict__ bs   = dir ? b_b : b_f;
    float*          __restrict__ hout = dir ? hb : hf;

    // register-resident weight row: 32 x h8 named SSA values (128 VGPRs)
    const h8_t* b8 = (const h8_t*)wreg2 + (size_t)(dir * 2 + half) * 16384;
    LDW(0); LDW(1); LDW(2); LDW(3); LDW(4); LDW(5); LDW(6); LDW(7);

    const float bias = bs[row];

    if (q < 32) hbuf8[q] = (h8_t)(_Float16)0.f;
    float c = 0.f;
    __syncthreads();

    const long tstr = 64 * 1024;
    const long hstr = 64 * 256;
    const int  t0   = dir ? (T_ - 1) : 0;
    const _Float16* gp = gin + (size_t)t0 * tstr + (size_t)b * 1024 + row;
    float*          hp = hout + (size_t)t0 * hstr + (size_t)b * 256 + half * 128 + q;
    const long gstep = dir ? -tstr : tstr;
    const long hstep = dir ? -hstr : hstr;

    // mailbox: 128 uints per pair per step = [pair][s][half][64]
    unsigned int* hexPub = hex + (size_t)pair * 65536 + (size_t)half * 64 + (q >> 1);
    const int pi = (q >= 128 && q < 192) ? (q - 128) : 0;
    const unsigned int* hexPoll =
        hex + (size_t)pair * 65536 + (size_t)(1 - half) * 64 + pi;
    const int pdst = (1 - half) * 64 + pi;

    const h8_t* HB = hbuf8;
    unsigned int* hbufU = (unsigned int*)hbuf8;
    _Float16*    hbufH = (_Float16*)hbuf8;

    _Float16 gc0 = gp[0];

    for (int s = 0; s < T_; ++s) {
        _Float16 gn0 = gp[gstep];   // prefetch; safe overread on last step

        float a0 = 0.f, a1 = 0.f, a2 = 0.f, a3 = 0.f;
        VBLK(0, 0); VBLK(1, 1); VBLK(2, 2); VBLK(3, 3);
        VBLK(4, 4); VBLK(5, 5); VBLK(6, 6); VBLK(7, 7);

        gbuf[q] = bias + (float)gc0 + ((a0 + a1) + (a2 + a3));
        __syncthreads();

        if (q < 128) {
            float gi = gbuf[q], gf = gbuf[128 + q];
            float gg = gbuf[256 + q], go = gbuf[384 + q];
            float si = 1.f / (1.f + expf(-gi));
            float sf = 1.f / (1.f + expf(-gf));
            float so = 1.f / (1.f + expf(-go));
            c = sf * c + si * tanhf(gg);
            float h = so * tanhf(c);
            hp[0] = h;
            hbufH[half * 128 + q] = (_Float16)h;
            if (s < T_ - 1) {
                float hn = __shfl_down(h, 1, 64);   // pairs never straddle a wave
                if ((q & 1) == 0) {
                    h2_t pk; pk[0] = (_Float16)h; pk[1] = (_Float16)hn;
                    __hip_atomic_store(hexPub + (size_t)s * 128,
                                       __builtin_bit_cast(unsigned int, pk),
                                       __ATOMIC_RELAXED, __HIP_MEMORY_SCOPE_AGENT);
                }
            }
        } else if (q < 192 && s < T_ - 1) {
            const unsigned int* src = hexPoll + (size_t)s * 128;
            unsigned int u;
            int guard = 0;
            do {
                u = __hip_atomic_load(src, __ATOMIC_RELAXED,
                                      __HIP_MEMORY_SCOPE_AGENT);
            } while (u == 0xFFFFFFFFu && ++guard < (1 << 20));
            hbufU[pdst] = u;
        }
        gc0 = gn0;
        gp += gstep;
        hp += hstep;
        __syncthreads();
    }
}

// ---------------------------------------------------------------------------
// Kernel C: feats[m, o] = concat(hf[m], hb[m]) . w_out[o, :] + b_out[o]
// ---------------------------------------------------------------------------
__global__ __launch_bounds__(256)
void feats_proj(const float* __restrict__ hf, const float* __restrict__ hb,
                const float* __restrict__ w_out, const float* __restrict__ b_out,
                float* __restrict__ feats)
{
    const int lane = threadIdx.x & 63;
    const int wv   = threadIdx.x >> 6;
    const int m    = blockIdx.x * 4 + wv;
    const int o    = lane & 15;
    const int qq   = lane >> 4;

    const float* hsrc = (qq < 2) ? (hf + (size_t)m * 256 + qq * 128)
                                 : (hb + (size_t)m * 256 + (qq - 2) * 128);
    const float4* h4 = (const float4*)hsrc;
    const float4* w4 = (const float4*)(w_out + o * 512 + qq * 128);

    float acc = 0.f;
    #pragma unroll
    for (int i = 0; i < 32; ++i) {
        float4 hv = h4[i], wvv = w4[i];
        acc = fmaf(hv.x, wvv.x, acc);
        acc = fmaf(hv.y, wvv.y, acc);
        acc = fmaf(hv.z, wvv.z, acc);
        acc = fmaf(hv.w, wvv.w, acc);
    }
    acc += __shfl_xor(acc, 16, 64);
    acc += __shfl_xor(acc, 32, 64);
    if (lane < 16) feats[(size_t)m * 16 + o] = acc + b_out[o];
}

// ---------------------------------------------------------------------------
// Kernel D: Viterbi + backtrace.
// ---------------------------------------------------------------------------
__global__ __launch_bounds__(64)
void viterbi(const float* __restrict__ feats, const float* __restrict__ trans,
             float* __restrict__ out)
{
    __shared__ unsigned char bp[T_][16];
    const int b    = blockIdx.x;
    const int lane = threadIdx.x;
    const int l15  = lane & 15;

    float tr[16];
    #pragma unroll
    for (int p = 0; p < 16; ++p)
        tr[p] = (lane < 16) ? trans[lane * 16 + p] : 0.f;

    float fv = (lane == START_) ? 0.f : NEG_;

    for (int t4 = 0; t4 < T_; t4 += 4) {
        float fblk = feats[((size_t)(t4 + (lane >> 4)) * 64 + b) * 16 + l15];
        #pragma unroll
        for (int tt = 0; tt < 4; ++tt) {
            const int t = t4 + tt;
            float best = -3.4e38f; int arg = 0;
            #pragma unroll
            for (int p = 0; p < 16; ++p) {
                float s = __shfl(fv, p, 64) + tr[p];
                if (s > best) { best = s; arg = p; }
            }
            float ft = __shfl(fblk, tt * 16 + l15, 64);
            if (lane < 16) {
                fv = best + ft;
                bp[t][lane] = (unsigned char)arg;
            }
        }
    }

    float term = fv + ((lane < 16) ? trans[STOP_ * 16 + lane] : 0.f);
    float v  = (lane < 16) ? term : -3.4e38f;
    int  idx = (lane < 16) ? lane : (1 << 20);
    #pragma unroll
    for (int off = 1; off < 64; off <<= 1) {
        float v2 = __shfl_xor(v, off, 64);
        int   i2 = __shfl_xor(idx, off, 64);
        if (v2 > v || (v2 == v && i2 < idx)) { v = v2; idx = i2; }
    }
    __syncthreads();
    if (lane == 0) {
        out[b] = v;
        int tag = idx;
        for (int t = T_ - 1; t >= 0; --t) {
            out[64 + (size_t)t * 64 + b] = (float)tag;
            tag = bp[t][tag];
        }
    }
}

// ---------------------------------------------------------------------------
extern "C" void kernel_launch(void* const* d_in, const int* in_sizes, int n_in,
                              void* d_out, int out_size, void* d_ws, size_t ws_size,
                              hipStream_t stream) {
    const int*   sentence = (const int*)d_in[0];
    const float* emb      = (const float*)d_in[1];
    const float* w_ih_f   = (const float*)d_in[2];
    const float* w_hh_f   = (const float*)d_in[3];
    const float* b_f      = (const float*)d_in[4];
    const float* w_ih_b   = (const float*)d_in[5];
    const float* w_hh_b   = (const float*)d_in[6];
    const float* b_b      = (const float*)d_in[7];
    const float* w_out    = (const float*)d_in[8];
    const float* b_out    = (const float*)d_in[9];
    const float* trans    = (const float*)d_in[10];
    float* out = (float*)d_out;

    // workspace: gin_f|gin_b (fp16 64MB ea) | hf|hb (fp32 32MB ea) |
    //            feats (2MB) | wih16 (1MB) | wreg2 (1MB) | hex mailbox (32MB)
    _Float16* gin_f = (_Float16*)d_ws;
    _Float16* gin_b = gin_f + (size_t)T_ * B_ * G_;
    float* hf    = (float*)(gin_b + (size_t)T_ * B_ * G_);
    float* hb    = hf + (size_t)T_ * B_ * H_;
    float* feats = hb + (size_t)T_ * B_ * H_;
    _Float16* wih16 = (_Float16*)(feats + (size_t)T_ * B_ * K_);
    _Float16* wreg2 = wih16 + 524288;
    unsigned int* hex = (unsigned int*)(wreg2 + 524288);

    prep_weights<<<320, 256, 0, stream>>>(w_hh_f, w_hh_b, w_ih_f, w_ih_b,
                                          wreg2, wih16);
    gates_mfma<<<dim3(512, 2), 256, 0, stream>>>(sentence, emb, wih16,
                                                 gin_f, gin_b);
    hipMemsetAsync(hex, 0xFF, (size_t)33554432, stream);   // prime sentinels
    lstm_pair<<<256, 512, 0, stream>>>(gin_f, gin_b, wreg2, b_f, b_b,
                                       hf, hb, hex);
    feats_proj<<<8192, 256, 0, stream>>>(hf, hb, w_out, b_out, feats);
    viterbi<<<64, 64, 0, stream>>>(feats, trans, out);
}